// Round 2
// baseline (226.778 us; speedup 1.0000x reference)
//
#include <hip/hip_runtime.h>
#include <math.h>

#define BATCH 32
#define HW (512*512)
#define TILE 128
#define NTILES (HW / TILE)   // 2048
#define GRID1 1024           // 2 tiles per block

// ws layout (floats): [0..1023] G[32][32], [1024] N1[32], [1056] N2[32],
// [1088] PP[32], [1120] P1[32], [1152] P2[32]  -> 1184 floats total

__device__ __forceinline__ float fsigmoid(float x) {
    float e = __builtin_amdgcn_exp2f(-x * 1.44269504088896340736f);
    return __builtin_amdgcn_rcpf(1.0f + e);
}

// XOR swizzle in bits 2..4 of the column (keeps float4 alignment, col < 128).
__device__ __forceinline__ int swf(int b) {
    return ((b >> 2) << 2) ^ ((b & 3) << 3);
}

__global__ __launch_bounds__(256) void cos_loss_main(
    const float* __restrict__ x1, const float* __restrict__ x2,
    const float* __restrict__ mk, float* __restrict__ ws)
{
    __shared__ float s1q[BATCH * TILE];
    __shared__ float s2q[BATCH * TILE];

    const int t    = threadIdx.x;
    const int w    = t >> 6;        // wave 0..3
    const int lane = t & 63;
    const int half = lane >> 5;     // sub-row within a pass
    const int p4   = (lane & 31) * 4;
    const int bi   = lane >> 3;     // gram 4-row block 0..7
    const int di   = lane & 7;      // gram 4-col block 0..7

    float gacc[4][4];
    #pragma unroll
    for (int i = 0; i < 4; ++i)
        #pragma unroll
        for (int j = 0; j < 4; ++j) gacc[i][j] = 0.f;

    float n1a[4], n2a[4], ppa[4], p1a[4], p2a[4];
    #pragma unroll
    for (int k = 0; k < 4; ++k) { n1a[k]=0.f; n2a[k]=0.f; ppa[k]=0.f; p1a[k]=0.f; p2a[k]=0.f; }

    // loop-invariant swizzled LDS base addresses for phase B
    int abase[4], bbase[4];
    #pragma unroll
    for (int i = 0; i < 4; ++i) {
        int ra = bi * 4 + i;  abase[i] = ra * TILE + swf(ra);
        int rb = di * 4 + i;  bbase[i] = rb * TILE + swf(rb);
    }

    for (int tile = blockIdx.x; tile < NTILES; tile += GRID1) {
        const int base = tile * TILE;
        __syncthreads();   // prev-iter LDS readers done before overwrite

        // ---- Phase A: load, sigmoid^2 -> LDS; fused row sums (mask binary)
        #pragma unroll 2
        for (int k = 0; k < 4; ++k) {
            int b = w * 8 + k * 2 + half;
            unsigned idx = (unsigned)b * HW + base + p4;
            float4 v1 = *(const float4*)(x1 + idx);
            float4 v2 = *(const float4*)(x2 + idx);
            float4 vm = *(const float4*)(mk + idx);
            float4 q1, q2;
            { float s = fsigmoid(v1.x); q1.x = s*s; }
            { float s = fsigmoid(v1.y); q1.y = s*s; }
            { float s = fsigmoid(v1.z); q1.z = s*s; }
            { float s = fsigmoid(v1.w); q1.w = s*s; }
            { float s = fsigmoid(v2.x); q2.x = s*s; }
            { float s = fsigmoid(v2.y); q2.y = s*s; }
            { float s = fsigmoid(v2.z); q2.z = s*s; }
            { float s = fsigmoid(v2.w); q2.w = s*s; }
            n1a[k] += (q1.x + q1.y) + (q1.z + q1.w);
            n2a[k] += (q2.x + q2.y) + (q2.z + q2.w);
            p1a[k] = fmaf(vm.x, q1.x, fmaf(vm.y, q1.y, fmaf(vm.z, q1.z, fmaf(vm.w, q1.w, p1a[k]))));
            p2a[k] = fmaf(vm.x, q2.x, fmaf(vm.y, q2.y, fmaf(vm.z, q2.z, fmaf(vm.w, q2.w, p2a[k]))));
            ppa[k] = fmaf(vm.x, q1.x*q2.x, fmaf(vm.y, q1.y*q2.y,
                     fmaf(vm.z, q1.z*q2.z, fmaf(vm.w, q1.w*q2.w, ppa[k]))));
            int col = p4 ^ swf(b);
            *(float4*)&s1q[b * TILE + col] = q1;
            *(float4*)&s2q[b * TILE + col] = q2;
        }
        __syncthreads();

        // ---- Phase B: Gram accumulation; wave w covers positions [32w,32w+32)
        const int pb = w * 32;
        #pragma unroll 2
        for (int ps = 0; ps < 32; ps += 4) {
            int p = pb + ps;
            float4 av[4], bv[4];
            #pragma unroll
            for (int i = 0; i < 4; ++i) {
                av[i] = *(const float4*)&s1q[abase[i] ^ p];
                bv[i] = *(const float4*)&s2q[bbase[i] ^ p];
            }
            #pragma unroll
            for (int i = 0; i < 4; ++i)
                #pragma unroll
                for (int j = 0; j < 4; ++j) {
                    gacc[i][j] = fmaf(av[i].x, bv[j].x, gacc[i][j]);
                    gacc[i][j] = fmaf(av[i].y, bv[j].y, gacc[i][j]);
                    gacc[i][j] = fmaf(av[i].z, bv[j].z, gacc[i][j]);
                    gacc[i][j] = fmaf(av[i].w, bv[j].w, gacc[i][j]);
                }
        }
    }

    // ---- flush fused row sums: reduce over the 32 lanes sharing a (k,half) row
    #pragma unroll
    for (int k = 0; k < 4; ++k) {
        float v0 = n1a[k], v1 = n2a[k], v2 = ppa[k], v3 = p1a[k], v4 = p2a[k];
        #pragma unroll
        for (int off = 1; off < 32; off <<= 1) {
            v0 += __shfl_xor(v0, off);
            v1 += __shfl_xor(v1, off);
            v2 += __shfl_xor(v2, off);
            v3 += __shfl_xor(v3, off);
            v4 += __shfl_xor(v4, off);
        }
        if ((lane & 31) == 0) {
            int b = w * 8 + k * 2 + half;
            atomicAdd(&ws[1024 + b], v0);
            atomicAdd(&ws[1056 + b], v1);
            atomicAdd(&ws[1088 + b], v2);
            atomicAdd(&ws[1120 + b], v3);
            atomicAdd(&ws[1152 + b], v4);
        }
    }

    // ---- flush Gram: merge 4 waves via LDS atomics, then global atomics
    __syncthreads();
    float* Gl = s1q;   // reuse (4096 floats available, need 1024)
    Gl[t] = 0.f; Gl[t + 256] = 0.f; Gl[t + 512] = 0.f; Gl[t + 768] = 0.f;
    __syncthreads();
    #pragma unroll
    for (int i = 0; i < 4; ++i)
        #pragma unroll
        for (int j = 0; j < 4; ++j)
            atomicAdd(&Gl[(bi * 4 + i) * BATCH + (di * 4 + j)], gacc[i][j]);
    __syncthreads();
    #pragma unroll
    for (int r = 0; r < 4; ++r)
        atomicAdd(&ws[t + r * 256], Gl[t + r * 256]);
}

__global__ __launch_bounds__(1024) void cos_loss_finalize(
    const float* __restrict__ ws, float* __restrict__ out)
{
    __shared__ float sn[BATCH];
    __shared__ float sp[BATCH];
    __shared__ float red[16];

    const int t = threadIdx.x;        // 0..1023
    const int b = t >> 5, d = t & 31;

    const float* G  = ws;
    const float* N1 = ws + 1024;
    const float* N2 = ws + 1056;
    const float* PP = ws + 1088;
    const float* P1 = ws + 1120;
    const float* P2 = ws + 1152;

    // sim[b][d], zero on diagonal
    float sim = 0.f;
    if (b != d) sim = sqrtf(G[t]) / (sqrtf(N1[b]) * sqrtf(N2[d]));
    #pragma unroll
    for (int off = 1; off < 32; off <<= 1) sim += __shfl_xor(sim, off);
    if (d == 0) sn[b] = sim;
    if (t < BATCH) sp[t] = sqrtf(PP[t]) / (sqrtf(P1[t]) * sqrtf(P2[t]));
    __syncthreads();

    // loss[i][j] with i=b (sn), j=d (sp); mean over 1024 entries
    float spj = sp[d], sni = sn[b];
    float loss = -logf(spj / (spj + sni));
    #pragma unroll
    for (int off = 1; off < 64; off <<= 1) loss += __shfl_xor(loss, off);
    if ((t & 63) == 0) red[t >> 6] = loss;
    __syncthreads();
    if (t < 16) {
        float v = red[t];
        #pragma unroll
        for (int off = 1; off < 16; off <<= 1) v += __shfl_xor(v, off);
        if (t == 0) out[0] = v * (1.0f / 1024.0f);
    }
}

extern "C" void kernel_launch(void* const* d_in, const int* in_sizes, int n_in,
                              void* d_out, int out_size, void* d_ws, size_t ws_size,
                              hipStream_t stream)
{
    const float* x1 = (const float*)d_in[0];
    const float* x2 = (const float*)d_in[1];
    const float* mk = (const float*)d_in[2];
    float* out = (float*)d_out;
    float* ws  = (float*)d_ws;

    hipMemsetAsync(ws, 0, 1184 * sizeof(float), stream);
    cos_loss_main<<<GRID1, 256, 0, stream>>>(x1, x2, mk, ws);
    cos_loss_finalize<<<1, 1024, 0, stream>>>(ws, out);
}

// Round 3
// 70.887 us; speedup vs baseline: 3.1991x; 3.1991x over previous
//
#include <hip/hip_runtime.h>
#include <math.h>

#define BATCH 32
#define HW (512*512)
#define TILE 128
#define NTILES (HW / TILE)   // 2048
#define MAXGRID 1024
#define SLICE 1184           // floats per block partial: G[1024] + 5*32 row sums

// slice layout (floats): [0..1023] G[32][32], [1024] N1[32], [1056] N2[32],
// [1088] PP[32], [1120] P1[32], [1152] P2[32]

__device__ __forceinline__ float fsigmoid(float x) {
    float e = __builtin_amdgcn_exp2f(-x * 1.44269504088896340736f);
    return __builtin_amdgcn_rcpf(1.0f + e);
}

// XOR swizzle in bits 2..4 of the column (keeps float4 alignment, col < 128).
__device__ __forceinline__ int swf(int b) {
    return ((b >> 2) << 2) ^ ((b & 3) << 3);
}

__global__ __launch_bounds__(256) void cos_loss_main(
    const float* __restrict__ x1, const float* __restrict__ x2,
    const float* __restrict__ mk, float* __restrict__ ws)
{
    __shared__ float s1q[BATCH * TILE];
    __shared__ float s2q[BATCH * TILE];

    const int t    = threadIdx.x;
    const int w    = t >> 6;        // wave 0..3
    const int lane = t & 63;
    const int half = lane >> 5;     // sub-row within a pass
    const int p4   = (lane & 31) * 4;
    const int bi   = lane >> 3;     // gram 4-row block 0..7
    const int di   = lane & 7;      // gram 4-col block 0..7

    float gacc[4][4];
    #pragma unroll
    for (int i = 0; i < 4; ++i)
        #pragma unroll
        for (int j = 0; j < 4; ++j) gacc[i][j] = 0.f;

    float n1a[4], n2a[4], ppa[4], p1a[4], p2a[4];
    #pragma unroll
    for (int k = 0; k < 4; ++k) { n1a[k]=0.f; n2a[k]=0.f; ppa[k]=0.f; p1a[k]=0.f; p2a[k]=0.f; }

    // loop-invariant swizzled LDS base addresses for phase B
    int abase[4], bbase[4];
    #pragma unroll
    for (int i = 0; i < 4; ++i) {
        int ra = bi * 4 + i;  abase[i] = ra * TILE + swf(ra);
        int rb = di * 4 + i;  bbase[i] = rb * TILE + swf(rb);
    }

    for (int tile = blockIdx.x; tile < NTILES; tile += gridDim.x) {
        const int base = tile * TILE;
        __syncthreads();   // prev-iter LDS readers done before overwrite

        // ---- Phase A: load, sigmoid^2 -> LDS; fused row sums (mask binary)
        #pragma unroll 2
        for (int k = 0; k < 4; ++k) {
            int b = w * 8 + k * 2 + half;
            unsigned idx = (unsigned)b * HW + base + p4;
            float4 v1 = *(const float4*)(x1 + idx);
            float4 v2 = *(const float4*)(x2 + idx);
            float4 vm = *(const float4*)(mk + idx);
            float4 q1, q2;
            { float s = fsigmoid(v1.x); q1.x = s*s; }
            { float s = fsigmoid(v1.y); q1.y = s*s; }
            { float s = fsigmoid(v1.z); q1.z = s*s; }
            { float s = fsigmoid(v1.w); q1.w = s*s; }
            { float s = fsigmoid(v2.x); q2.x = s*s; }
            { float s = fsigmoid(v2.y); q2.y = s*s; }
            { float s = fsigmoid(v2.z); q2.z = s*s; }
            { float s = fsigmoid(v2.w); q2.w = s*s; }
            n1a[k] += (q1.x + q1.y) + (q1.z + q1.w);
            n2a[k] += (q2.x + q2.y) + (q2.z + q2.w);
            p1a[k] = fmaf(vm.x, q1.x, fmaf(vm.y, q1.y, fmaf(vm.z, q1.z, fmaf(vm.w, q1.w, p1a[k]))));
            p2a[k] = fmaf(vm.x, q2.x, fmaf(vm.y, q2.y, fmaf(vm.z, q2.z, fmaf(vm.w, q2.w, p2a[k]))));
            ppa[k] = fmaf(vm.x, q1.x*q2.x, fmaf(vm.y, q1.y*q2.y,
                     fmaf(vm.z, q1.z*q2.z, fmaf(vm.w, q1.w*q2.w, ppa[k]))));
            int col = p4 ^ swf(b);
            *(float4*)&s1q[b * TILE + col] = q1;
            *(float4*)&s2q[b * TILE + col] = q2;
        }
        __syncthreads();

        // ---- Phase B: Gram accumulation; wave w covers positions [32w,32w+32)
        const int pb = w * 32;
        #pragma unroll 2
        for (int ps = 0; ps < 32; ps += 4) {
            int p = pb + ps;
            float4 av[4], bv[4];
            #pragma unroll
            for (int i = 0; i < 4; ++i) {
                av[i] = *(const float4*)&s1q[abase[i] ^ p];
                bv[i] = *(const float4*)&s2q[bbase[i] ^ p];
            }
            #pragma unroll
            for (int i = 0; i < 4; ++i)
                #pragma unroll
                for (int j = 0; j < 4; ++j) {
                    gacc[i][j] = fmaf(av[i].x, bv[j].x, gacc[i][j]);
                    gacc[i][j] = fmaf(av[i].y, bv[j].y, gacc[i][j]);
                    gacc[i][j] = fmaf(av[i].z, bv[j].z, gacc[i][j]);
                    gacc[i][j] = fmaf(av[i].w, bv[j].w, gacc[i][j]);
                }
        }
    }

    float* slice = ws + (size_t)blockIdx.x * SLICE;

    // ---- flush fused row sums: plain stores to this block's own slice
    #pragma unroll
    for (int k = 0; k < 4; ++k) {
        float v0 = n1a[k], v1 = n2a[k], v2 = ppa[k], v3 = p1a[k], v4 = p2a[k];
        #pragma unroll
        for (int off = 1; off < 32; off <<= 1) {
            v0 += __shfl_xor(v0, off);
            v1 += __shfl_xor(v1, off);
            v2 += __shfl_xor(v2, off);
            v3 += __shfl_xor(v3, off);
            v4 += __shfl_xor(v4, off);
        }
        if ((lane & 31) == 0) {
            int b = w * 8 + k * 2 + half;
            slice[1024 + b] = v0;
            slice[1056 + b] = v1;
            slice[1088 + b] = v2;
            slice[1120 + b] = v3;
            slice[1152 + b] = v4;
        }
    }

    // ---- flush Gram: merge 4 waves via LDS atomics, then plain stores
    __syncthreads();
    float* Gl = s1q;   // reuse
    Gl[t] = 0.f; Gl[t + 256] = 0.f; Gl[t + 512] = 0.f; Gl[t + 768] = 0.f;
    __syncthreads();
    #pragma unroll
    for (int i = 0; i < 4; ++i)
        #pragma unroll
        for (int j = 0; j < 4; ++j)
            atomicAdd(&Gl[(bi * 4 + i) * BATCH + (di * 4 + j)], gacc[i][j]);
    __syncthreads();
    #pragma unroll
    for (int r = 0; r < 4; ++r)
        slice[t + r * 256] = Gl[t + r * 256];
}

// Sum ns slices -> red[8][1184] (chunked over blockIdx.y, no contention)
__global__ __launch_bounds__(256) void cos_loss_reduce(
    const float* __restrict__ ws, int ns, float* __restrict__ red)
{
    int e  = blockIdx.x * 256 + threadIdx.x;
    int kc = blockIdx.y;
    int k0 = (kc * ns) >> 3, k1 = ((kc + 1) * ns) >> 3;
    if (e >= SLICE) return;
    float s0 = 0.f, s1 = 0.f;
    int k = k0;
    for (; k + 1 < k1; k += 2) {
        s0 += ws[(size_t)k * SLICE + e];
        s1 += ws[(size_t)(k + 1) * SLICE + e];
    }
    if (k < k1) s0 += ws[(size_t)k * SLICE + e];
    red[kc * SLICE + e] = s0 + s1;
}

__global__ __launch_bounds__(1024) void cos_loss_finalize(
    const float* __restrict__ red, float* __restrict__ out)
{
    __shared__ float rs[160];   // N1 | N2 | PP | P1 | P2
    __shared__ float sn[BATCH];
    __shared__ float sp[BATCH];
    __shared__ float redsh[16];

    const int t = threadIdx.x;        // 0..1023
    const int b = t >> 5, d = t & 31;

    float g = 0.f;
    #pragma unroll
    for (int c = 0; c < 8; ++c) g += red[c * SLICE + t];
    if (t < 160) {
        float s = 0.f;
        #pragma unroll
        for (int c = 0; c < 8; ++c) s += red[c * SLICE + 1024 + t];
        rs[t] = s;
    }
    __syncthreads();

    // sim[b][d], zero on diagonal
    float sim = 0.f;
    if (b != d) sim = sqrtf(g) / (sqrtf(rs[b]) * sqrtf(rs[32 + d]));
    #pragma unroll
    for (int off = 1; off < 32; off <<= 1) sim += __shfl_xor(sim, off);
    if (d == 0) sn[b] = sim;
    if (t < BATCH) sp[t] = sqrtf(rs[64 + t]) / (sqrtf(rs[96 + t]) * sqrtf(rs[128 + t]));
    __syncthreads();

    // loss[i][j] with i=b (sn), j=d (sp); mean over 1024 entries
    float spj = sp[d], sni = sn[b];
    float loss = -logf(spj / (spj + sni));
    #pragma unroll
    for (int off = 1; off < 64; off <<= 1) loss += __shfl_xor(loss, off);
    if ((t & 63) == 0) redsh[t >> 6] = loss;
    __syncthreads();
    if (t < 16) {
        float v = redsh[t];
        #pragma unroll
        for (int off = 1; off < 16; off <<= 1) v += __shfl_xor(v, off);
        if (t == 0) out[0] = v * (1.0f / 1024.0f);
    }
}

extern "C" void kernel_launch(void* const* d_in, const int* in_sizes, int n_in,
                              void* d_out, int out_size, void* d_ws, size_t ws_size,
                              hipStream_t stream)
{
    const float* x1 = (const float*)d_in[0];
    const float* x2 = (const float*)d_in[1];
    const float* mk = (const float*)d_in[2];
    float* out = (float*)d_out;
    float* ws  = (float*)d_ws;

    // slices must fit in ws along with the 8*SLICE reduce buffer
    long wsf = (long)(ws_size / sizeof(float));
    int ns = (int)((wsf - 8 * SLICE) / SLICE);
    if (ns > MAXGRID) ns = MAXGRID;
    if (ns < 1) ns = 1;
    float* red = ws + (size_t)ns * SLICE;

    cos_loss_main<<<ns, 256, 0, stream>>>(x1, x2, mk, ws);
    cos_loss_reduce<<<dim3(5, 8), 256, 0, stream>>>(ws, ns, red);
    cos_loss_finalize<<<1, 1024, 0, stream>>>(red, out);
}